// Round 2
// baseline (223.498 us; speedup 1.0000x reference)
//
#include <hip/hip_runtime.h>

// Ontomap: loss = sum((n2f@n_e - f_e)^2) + sum((m2f@m_e - f_e)^2)
// B = 1,048,576 samples, D = 64.
// Strategy: f16 MFMA (32x32x16) batched matvec, gathers loaded directly in
// MFMA fragment layout (no LDS), fp32 f_e compared in C/D layout,
// per-lane loss accumulator -> wave reduce -> atomicAdd.

typedef _Float16 half8 __attribute__((ext_vector_type(8)));
typedef __fp16  fp16x2 __attribute__((ext_vector_type(2)));
typedef float floatx16 __attribute__((ext_vector_type(16)));

#define NBLOCKS 1024
#define WAVES_PER_BLOCK 4
#define SAMPLES_PER_BLOCK 128   // 4 waves * 32 samples

__device__ inline half8 cvt8(float4 a, float4 b) {
    union { half8 h; fp16x2 h2[4]; } u;
    u.h2[0] = __builtin_amdgcn_cvt_pkrtz(a.x, a.y);
    u.h2[1] = __builtin_amdgcn_cvt_pkrtz(a.z, a.w);
    u.h2[2] = __builtin_amdgcn_cvt_pkrtz(b.x, b.y);
    u.h2[3] = __builtin_amdgcn_cvt_pkrtz(b.z, b.w);
    return u.h;
}

__global__ __launch_bounds__(256, 2) void ontomap_kernel(
    const int* __restrict__ pos_n, const int* __restrict__ pos_m,
    const int* __restrict__ pos_f,
    const float* __restrict__ nci, const float* __restrict__ fma_emb,
    const float* __restrict__ n2f, const float* __restrict__ m2f,
    float* __restrict__ out, int iters)
{
    const int lane = threadIdx.x & 63;
    const int wave = threadIdx.x >> 6;
    const int l31  = lane & 31;
    const int hi   = lane >> 5;     // 0 or 1
    const int kbase = hi * 8;       // k offset within a 16-wide K step

    // ---- Preload B fragments for both projection matrices.
    // B[k][n] = M[n][k]; lane holds n = nt*32 + l31, k = t*16 + hi*8 + j.
    half8 Bn[2][4], Bm[2][4];
#pragma unroll
    for (int nt = 0; nt < 2; ++nt) {
#pragma unroll
        for (int t = 0; t < 4; ++t) {
            const float* p = n2f + (nt * 32 + l31) * 64 + t * 16 + kbase;
            Bn[nt][t] = cvt8(*(const float4*)p, *(const float4*)(p + 4));
            const float* q = m2f + (nt * 32 + l31) * 64 + t * 16 + kbase;
            Bm[nt][t] = cvt8(*(const float4*)q, *(const float4*)(q + 4));
        }
    }

    float loss = 0.0f;

    // Prefetch indices for iteration 0 (lanes 32-63 load duplicates of 0-31).
    int in_, im_, if_;
    {
        int s = blockIdx.x * SAMPLES_PER_BLOCK + wave * 32 + l31;
        in_ = pos_n[s]; im_ = pos_m[s]; if_ = pos_f[s];
    }

#pragma unroll 1
    for (int it = 0; it < iters; ++it) {
        const int in0 = in_, im0 = im_, if0 = if_;
        if (it + 1 < iters) {
            int s = ((it + 1) * NBLOCKS + blockIdx.x) * SAMPLES_PER_BLOCK
                    + wave * 32 + l31;
            in_ = pos_n[s]; im_ = pos_m[s]; if_ = pos_f[s];
        }

        // A gathers in fragment layout: sample m = l31, k = t*16 + hi*8 + j.
        const float* pn = nci + (long)in0 * 64 + kbase;
        const float* pm = nci + (long)im0 * 64 + kbase;

        floatx16 aN0{}, aN1{}, aM0{}, aM1{};
#pragma unroll
        for (int t = 0; t < 4; ++t) {
            half8 aF = cvt8(*(const float4*)(pn + t * 16),
                            *(const float4*)(pn + t * 16 + 4));
            aN0 = __builtin_amdgcn_mfma_f32_32x32x16_f16(aF, Bn[0][t], aN0, 0, 0, 0);
            aN1 = __builtin_amdgcn_mfma_f32_32x32x16_f16(aF, Bn[1][t], aN1, 0, 0, 0);
            half8 bF = cvt8(*(const float4*)(pm + t * 16),
                            *(const float4*)(pm + t * 16 + 4));
            aM0 = __builtin_amdgcn_mfma_f32_32x32x16_f16(bF, Bm[0][t], aM0, 0, 0, 0);
            aM1 = __builtin_amdgcn_mfma_f32_32x32x16_f16(bF, Bm[1][t], aM1, 0, 0, 0);
        }

        // Loss phase: C/D layout col = l31 (tile0) / 32+l31 (tile1),
        // row(sample-in-group) = (r&3) + 8*(r>>2) + 4*hi.
#pragma unroll
        for (int r = 0; r < 16; ++r) {
            const int mrow = (r & 3) + 8 * (r >> 2) + 4 * hi;
            const int fid  = __shfl(if0, mrow, 64);  // lane mrow (<32) holds pos_f[base+mrow]
            const float* pf = fma_emb + (long)fid * 64 + l31;
            const float f0 = pf[0];    // dims 0..31
            const float f1 = pf[32];   // dims 32..63
            float d;
            d = aN0[r] - f0; loss = fmaf(d, d, loss);
            d = aM0[r] - f0; loss = fmaf(d, d, loss);
            d = aN1[r] - f1; loss = fmaf(d, d, loss);
            d = aM1[r] - f1; loss = fmaf(d, d, loss);
        }
    }

    // Wave reduction, then one atomic per wave.
#pragma unroll
    for (int o = 32; o > 0; o >>= 1) loss += __shfl_xor(loss, o, 64);
    if (lane == 0) atomicAdd(out, loss);
}

extern "C" void kernel_launch(void* const* d_in, const int* in_sizes, int n_in,
                              void* d_out, int out_size, void* d_ws, size_t ws_size,
                              hipStream_t stream) {
    const int*   pos_n   = (const int*)d_in[0];
    const int*   pos_m   = (const int*)d_in[1];
    const int*   pos_f   = (const int*)d_in[2];
    const float* nci_emb = (const float*)d_in[3];
    const float* fma_emb = (const float*)d_in[4];
    const float* n2f_mat = (const float*)d_in[5];
    const float* m2f_mat = (const float*)d_in[6];
    float* out = (float*)d_out;

    const int B = in_sizes[0];
    const int iters = B / (NBLOCKS * SAMPLES_PER_BLOCK);  // 1,048,576 -> 8

    (void)hipMemsetAsync(out, 0, sizeof(float), stream);
    ontomap_kernel<<<NBLOCKS, 256, 0, stream>>>(
        pos_n, pos_m, pos_f, nci_emb, fma_emb, n2f_mat, m2f_mat, out, iters);
}